// Round 5
// baseline (234.813 us; speedup 1.0000x reference)
//
#include <hip/hip_runtime.h>
#include <hip/hip_bf16.h>

// ---------------------------------------------------------------------------
// WindowAttention: B=32 RES=56 C=128 HEADS=4 HD=32 WS=7 NW=8 NQ=64 WA=49
// fp32 I/O, bf16 MFMA internally.
// Pipeline: k_prep (weights->bf16) ; k_rpb (bias MLP -> C-fragment-ordered
// bf16 table) ; k_qkv (fused QKV GEMM, q->d_out interleaved, k/v->ws) ;
// k_attn (FUSED attention + output projection: 2 gather phases x 2 heads,
// LDS overlay reuses Kt/Vt/Sm space for Om/Pw, writes final output).
// d_out aliasing: q (bf16) lives in the first 12544B of each window's 25088B
// output slot; block (b,qi) reads all its q before storing its out slot.
// ---------------------------------------------------------------------------

typedef __bf16 bf16_t;
typedef __bf16 bf16x8 __attribute__((ext_vector_type(8)));
typedef __bf16 bf16x4 __attribute__((ext_vector_type(4)));
typedef float f32x4 __attribute__((ext_vector_type(4)));

static __device__ __forceinline__ f32x4 mfma_bf16(bf16x8 a, bf16x8 b, f32x4 c) {
  return __builtin_amdgcn_mfma_f32_16x16x32_bf16(a, b, c, 0, 0, 0);
}

static __device__ __forceinline__ bf16x8 cvt8(const float* __restrict__ p) {
  float4 a = *(const float4*)p;
  float4 b = *(const float4*)(p + 4);
  bf16x8 r;
  r[0] = (bf16_t)a.x; r[1] = (bf16_t)a.y; r[2] = (bf16_t)a.z; r[3] = (bf16_t)a.w;
  r[4] = (bf16_t)b.x; r[5] = (bf16_t)b.y; r[6] = (bf16_t)b.z; r[7] = (bf16_t)b.w;
  return r;
}

#define NB 32
#define RES 56
#define CH 128
#define NQ 64
#define WA 49
#define X0_ROWS (NB * RES * RES)       // 100352
#define SCALE 0.17677669529663687f     // 32^-0.5
#define SQRT32 5.656854249492381f

// ---------------------------------------------------------------------------
// K0: one-shot weight conversion fp32 -> bf16 (qkv_w 49152, proj_w 16384)
// ---------------------------------------------------------------------------
__global__ __launch_bounds__(256) void k_prep(
    const float* __restrict__ qkv_w, const float* __restrict__ proj_w,
    bf16_t* __restrict__ wq, bf16_t* __restrict__ pwb) {
  int i = blockIdx.x * 256 + threadIdx.x;
  if (i < 49152) wq[i] = (bf16_t)qkv_w[i];
  else if (i - 49152 < 16384) pwb[i - 49152] = (bf16_t)proj_w[i - 49152];
}

// ---------------------------------------------------------------------------
// K1: rpb MLP -> bf16 table in exact MFMA-C-fragment order:
// addr = (((qi*4+hh)*8 + nt)*256 + tid)*4 + r4, where for score (n,m):
// nt=m>>4, lr=m&15, wid=n>>4, lkg=(n>>2)&3, r4=n&3, tid=wid*64+lkg*16+lr.
// Pre-scaled by sqrt(32). Rows n>=49 never written (poison is finite, rows
// discarded downstream).
// ---------------------------------------------------------------------------
__global__ __launch_bounds__(256) void k_rpb(
    const float* __restrict__ c0, const float* __restrict__ c1,
    const float* __restrict__ w10, const float* __restrict__ b10,
    const float* __restrict__ w20, const float* __restrict__ b20,
    const float* __restrict__ w11, const float* __restrict__ b11,
    const float* __restrict__ w21, const float* __restrict__ b21,
    bf16_t* __restrict__ rpb2) {
  __shared__ float w1s[2][32][2], b1s[2][32], w2s[2][4][32], b2s[2][4];
  const int tid = threadIdx.x;
  if (tid < 64) {
    int s = tid >> 5, j = tid & 31;
    const float* w1p = s ? w11 : w10;
    const float* b1p = s ? b11 : b10;
    w1s[s][j][0] = w1p[j * 2];
    w1s[s][j][1] = w1p[j * 2 + 1];
    b1s[s][j] = b1p[j];
  }
  {
    int s = tid >> 7, rem = tid & 127, h = rem >> 5, j = rem & 31;
    w2s[s][h][j] = s ? w21[h * 32 + j] : w20[h * 32 + j];
  }
  if (tid < 8) {
    int s = tid >> 2, h = tid & 3;
    b2s[s][h] = s ? b21[h] : b20[h];
  }
  __syncthreads();

  int L = blockIdx.x * 256 + tid;      // < 64*49*128
  int m = L & 127;
  int n = (L >> 7) % WA;
  int qi = L / (128 * WA);
  int s = m >> 6, mi = m & 63;
  const float* cp = (s ? c1 : c0) + (((size_t)qi * WA + n) * 64 + mi) * 2;
  float cx = cp[0], cy = cp[1];
  float a0 = 0.f, a1 = 0.f, a2 = 0.f, a3 = 0.f;
#pragma unroll
  for (int j = 0; j < 32; ++j) {
    float h = fmaxf(w1s[s][j][0] * cx + w1s[s][j][1] * cy + b1s[s][j], 0.f);
    a0 += w2s[s][0][j] * h;
    a1 += w2s[s][1][j] * h;
    a2 += w2s[s][2][j] * h;
    a3 += w2s[s][3][j] * h;
  }
  int nt = m >> 4, lr = m & 15;
  int wid2 = n >> 4, lkg2 = (n >> 2) & 3, r4 = n & 3;
  int t2 = wid2 * 64 + lkg2 * 16 + lr;
  size_t base2 = (((size_t)(qi * 4) * 8 + nt) * 256 + t2) * 4 + r4;
  // head stride = 8*256*4 = 8192
  rpb2[base2]         = (bf16_t)((a0 + b2s[s][0]) * SQRT32);
  rpb2[base2 + 8192]  = (bf16_t)((a1 + b2s[s][1]) * SQRT32);
  rpb2[base2 + 16384] = (bf16_t)((a2 + b2s[s][2]) * SQRT32);
  rpb2[base2 + 24576] = (bf16_t)((a3 + b2s[s][3]) * SQRT32);
}

// ---------------------------------------------------------------------------
// K2: qkv GEMM. A staged once (fragments preloaded to regs, Asm reused as
// C-staging buffer), B = preconverted bf16 weights (plain uint4 copies),
// coalesced uint4 stores. grid 1600 x 256.
// ---------------------------------------------------------------------------
__global__ __launch_bounds__(256) void k_qkv(
    const float* __restrict__ x0, const float* __restrict__ x1,
    const bf16_t* __restrict__ wq, const float* __restrict__ bias,
    bf16_t* __restrict__ qout,          // d_out, interleaved window slots
    bf16_t* __restrict__ k0, bf16_t* __restrict__ v0,
    bf16_t* __restrict__ k1, bf16_t* __restrict__ v1) {
  __shared__ __align__(16) bf16_t Asm[64][136];   // A tile, then C staging
  __shared__ __align__(16) bf16_t Bsm[128][136];
  const int rb = blockIdx.x;           // 0..1599 (>=1568: x1 rows)
  const int tid = threadIdx.x;
  const size_t row0 = (size_t)rb * 64;
  const bool is_x0 = (rb < 1568);
  const int b_ = rb / 49;
  const int pix0 = (rb - b_ * 49) * 64;
  const int i1base = (rb - 1568) * 64;

  const float* src = is_x0 ? (x0 + row0 * CH)
                           : (x1 + (row0 - X0_ROWS) * CH);
#pragma unroll
  for (int i = 0; i < 4; ++i) {        // A: 64x128 cvt
    int uid = tid + 256 * i;
    int r = uid >> 4, cs = uid & 15;
    *(bf16x8*)&Asm[r][cs * 8] = cvt8(src + (size_t)r * CH + cs * 8);
  }
#pragma unroll
  for (int i = 0; i < 8; ++i) {        // B(cb0): plain bf16 copy
    int uid = tid + 256 * i;
    int r = uid >> 4, cs = uid & 15;
    *(uint4*)&Bsm[r][cs * 8] = *(const uint4*)(wq + (size_t)r * CH + cs * 8);
  }
  __syncthreads();

  const int wid = tid >> 6, l = tid & 63;
  const int lr = l & 15, lkg = l >> 4, lk = lkg * 8;
  const int myrow = wid * 16 + lkg * 4;

  bf16x8 af[4];
#pragma unroll
  for (int ks = 0; ks < 4; ++ks)
    af[ks] = *(const bf16x8*)&Asm[wid * 16 + lr][ks * 32 + lk];

  for (int cb = 0; cb < 3; ++cb) {
    f32x4 zero = {0.f, 0.f, 0.f, 0.f};
    f32x4 acc[8];
#pragma unroll
    for (int nt = 0; nt < 8; ++nt) acc[nt] = zero;
#pragma unroll
    for (int ks = 0; ks < 4; ++ks)
#pragma unroll
      for (int nt = 0; nt < 8; ++nt) {
        bf16x8 b = *(const bf16x8*)&Bsm[nt * 16 + lr][ks * 32 + lk];
        acc[nt] = mfma_bf16(af[ks], b, acc[nt]);
      }
    __syncthreads();                   // MFMA (and cb0 af-preload) done

    const bool emit = is_x0 || cb != 0;
    if (emit) {                        // C -> Asm space (bf16, +bias)
#pragma unroll
      for (int nt = 0; nt < 8; ++nt) {
        float bs = bias[cb * 128 + nt * 16 + lr];
#pragma unroll
        for (int r4 = 0; r4 < 4; ++r4)
          Asm[myrow + r4][nt * 16 + lr] = (bf16_t)(acc[nt][r4] + bs);
      }
    }
    __syncthreads();

    if (cb < 2) {                      // stage next B while storing C
#pragma unroll
      for (int i = 0; i < 8; ++i) {
        int uid = tid + 256 * i;
        int r = uid >> 4, cs = uid & 15;
        *(uint4*)&Bsm[r][cs * 8] =
            *(const uint4*)(wq + (size_t)(cb + 1) * 16384 + r * CH + cs * 8);
      }
    }
    if (emit) {                        // coalesced C store
#pragma unroll
      for (int i = 0; i < 4; ++i) {
        int uid = tid + 256 * i;
        int r = uid >> 4, cs = uid & 15;
        bf16_t* dptr;
        if (!is_x0) {
          dptr = (cb == 1 ? k1 : v1) + (size_t)(i1base + r) * CH;
        } else if (cb == 0) {
          int pix = pix0 + r;
          int rr = pix / 56, cc = pix - rr * 56;
          int wn = b_ * 64 + (rr / 7) * 8 + cc / 7;
          int nid = (rr % 7) * 7 + (cc % 7);
          dptr = qout + (size_t)wn * 12544 + nid * 128;
        } else {
          dptr = (cb == 1 ? k0 : v0) + (row0 + r) * CH;
        }
        *(uint4*)(dptr + cs * 8) = *(const uint4*)&Asm[r][cs * 8];
      }
    }
    __syncthreads();                   // Bsm ready / Asm free for next C
  }
}

// ---------------------------------------------------------------------------
// K3: FUSED attention + projection. block = (b, qi), 2048 blocks, 256 thr.
// Phase p=0: gather K/V ch 0..63, heads 0,1. Phase p=1: ch 64..127, heads
// 2,3. O kept in registers (C-layout) across phases. Then LDS overlay:
// Om (O bf16) in Kt space, Pw (proj weights) in Vt+Sm space; in-block proj
// GEMM; final fp32 store (+proj bias) into this window's d_out slot.
// ---------------------------------------------------------------------------
__global__ __launch_bounds__(256) void k_attn(
    const bf16_t* qin,                  // d_out interleaved, aliased
    const bf16_t* __restrict__ k0, const bf16_t* __restrict__ v0,
    const bf16_t* __restrict__ k1, const bf16_t* __restrict__ v1,
    const int* __restrict__ idx0, const int* __restrict__ idx1,
    const bf16_t* __restrict__ rpb2, const bf16_t* __restrict__ pw,
    const float* __restrict__ pb,
    float* attn_out) {                  // d_out, aliased
  __shared__ __align__(16) char smem[53248];
  bf16_t* Kt = (bf16_t*)smem;                  // [128][72]  18432B
  bf16_t* Vt = (bf16_t*)(smem + 18432);        // [64][136]  17408B
  bf16_t* Sm = (bf16_t*)(smem + 35840);        // [64][136]  17408B
  bf16_t* Om = (bf16_t*)smem;                  // overlay: [64][136] 17408B
  bf16_t* Pw = (bf16_t*)(smem + 18432);        // overlay: [128][136] 34816B

  const int bid = blockIdx.x;          // 2048 = 32*64
  const int qi = bid & 63;
  const int b = bid >> 6;
  const int tid = threadIdx.x;
  const int wn = bid;

  const int wid = tid >> 6, l = tid & 63;
  const int lr = l & 15, lkg = l >> 4, lk = lkg * 8;
  const int myrow = wid * 16 + lkg * 4;
  int qr = wid * 16 + lr;
  if (qr > WA - 1) qr = WA - 1;
  const bf16_t* qb = qin + (size_t)wn * 12544;

  f32x4 oreg[4][2];                    // [head][nt2] C-layout O
  float rsum[4][4];                    // [head][r4] 1/rowsum

  for (int p = 0; p < 2; ++p) {
    // ---- gather K/V channel slice p*64..p*64+63 (key lane-fastest)
#pragma unroll
    for (int i = 0; i < 4; ++i) {
      int uid = tid + 256 * i;         // 0..1023
      int key = uid & 127, seg = uid >> 7;
      size_t srcrow;
      const bf16_t *kbase, *vbase;
      if (key < 64) {
        srcrow = (size_t)b * 3136 + idx0[qi * 64 + key];
        kbase = k0; vbase = v0;
      } else {
        srcrow = (size_t)b * 64 + idx1[qi * 64 + key - 64];
        kbase = k1; vbase = v1;
      }
      size_t off = srcrow * CH + p * 64 + seg * 8;
      *(uint4*)&Kt[key * 72 + seg * 8] = *(const uint4*)(kbase + off);
      union { uint4 u; bf16_t h[8]; } cv;
      cv.u = *(const uint4*)(vbase + off);
#pragma unroll
      for (int e = 0; e < 8; ++e) Vt[(seg * 8 + e) * 136 + key] = cv.h[e];
    }
    // ---- preload this phase's Q fragments (ch p*64 .. +63)
    bf16x8 qf[2];
    qf[0] = *(const bf16x8*)&qb[qr * 128 + p * 64 + lk];
    qf[1] = *(const bf16x8*)&qb[qr * 128 + p * 64 + 32 + lk];
    __syncthreads();

#pragma unroll
    for (int lh = 0; lh < 2; ++lh) {
      const int hh = p * 2 + lh;
      // ---- acc init = rpb (C-fragment-ordered bf16 table, coalesced 8B)
      const bf16_t* rp = rpb2 + (((size_t)(qi * 4 + hh)) * 8) * 1024 + tid * 4;
      f32x4 acc[8];
#pragma unroll
      for (int nt = 0; nt < 8; ++nt) {
        bf16x4 v = *(const bf16x4*)(rp + nt * 1024);
        acc[nt][0] = (float)v[0]; acc[nt][1] = (float)v[1];
        acc[nt][2] = (float)v[2]; acc[nt][3] = (float)v[3];
      }
      // ---- QK^T
#pragma unroll
      for (int nt = 0; nt < 8; ++nt) {
        bf16x8 bfr = *(const bf16x8*)&Kt[(nt * 16 + lr) * 72 + lh * 32 + lk];
        acc[nt] = mfma_bf16(qf[lh], bfr, acc[nt]);
      }
      // ---- in-register softmax over 128 cols (16-lane shuffles)
      float mx[4] = {-1e30f, -1e30f, -1e30f, -1e30f};
#pragma unroll
      for (int nt = 0; nt < 8; ++nt)
#pragma unroll
        for (int r4 = 0; r4 < 4; ++r4) mx[r4] = fmaxf(mx[r4], acc[nt][r4]);
#pragma unroll
      for (int m = 1; m < 16; m <<= 1)
#pragma unroll
        for (int r4 = 0; r4 < 4; ++r4)
          mx[r4] = fmaxf(mx[r4], __shfl_xor(mx[r4], m));
      float sum[4] = {0.f, 0.f, 0.f, 0.f};
#pragma unroll
      for (int nt = 0; nt < 8; ++nt)
#pragma unroll
        for (int r4 = 0; r4 < 4; ++r4) {
          float pv = __expf(SCALE * (acc[nt][r4] - mx[r4]));
          acc[nt][r4] = pv;
          sum[r4] += pv;
        }
#pragma unroll
      for (int m = 1; m < 16; m <<= 1)
#pragma unroll
        for (int r4 = 0; r4 < 4; ++r4) sum[r4] += __shfl_xor(sum[r4], m);
#pragma unroll
      for (int r4 = 0; r4 < 4; ++r4)
        rsum[hh][r4] = __builtin_amdgcn_rcpf(sum[r4]);
      // ---- P -> Sm (wave-local rows; no barrier needed)
#pragma unroll
      for (int nt = 0; nt < 8; ++nt)
#pragma unroll
        for (int r4 = 0; r4 < 4; ++r4)
          Sm[(myrow + r4) * 136 + nt * 16 + lr] = (bf16_t)acc[nt][r4];
      // ---- PV
      f32x4 zero = {0.f, 0.f, 0.f, 0.f};
      f32x4 oacc[2];
      oacc[0] = zero; oacc[1] = zero;
#pragma unroll
      for (int ks = 0; ks < 4; ++ks) {
        bf16x8 pa = *(const bf16x8*)&Sm[(wid * 16 + lr) * 136 + ks * 32 + lk];
#pragma unroll
        for (int nt2 = 0; nt2 < 2; ++nt2) {
          bf16x8 vb = *(const bf16x8*)
              &Vt[(lh * 32 + nt2 * 16 + lr) * 136 + ks * 32 + lk];
          oacc[nt2] = mfma_bf16(pa, vb, oacc[nt2]);
        }
      }
      oreg[hh][0] = oacc[0];
      oreg[hh][1] = oacc[1];
    }
    __syncthreads();                   // Kt/Vt/Sm free for next phase/overlay
  }

  // ---- overlay: O (normalized, bf16) -> Om ; proj weights -> Pw
#pragma unroll
  for (int hh = 0; hh < 4; ++hh)
#pragma unroll
    for (int nt2 = 0; nt2 < 2; ++nt2)
#pragma unroll
      for (int r4 = 0; r4 < 4; ++r4)
        Om[(myrow + r4) * 136 + hh * 32 + nt2 * 16 + lr] =
            (bf16_t)(oreg[hh][nt2][r4] * rsum[hh][r4]);
#pragma unroll
  for (int i = 0; i < 8; ++i) {        // Pw: 128x128 bf16 copy
    int uid = tid + 256 * i;
    int r = uid >> 4, cs = uid & 15;
    *(uint4*)&Pw[r * 136 + cs * 8] = *(const uint4*)(pw + r * CH + cs * 8);
  }
  __syncthreads();

  // ---- in-block projection: out = Om @ pw.T + pb
  f32x4 zero = {0.f, 0.f, 0.f, 0.f};
  f32x4 acc[8];
#pragma unroll
  for (int nt = 0; nt < 8; ++nt) acc[nt] = zero;
#pragma unroll
  for (int ks = 0; ks < 4; ++ks) {
    bf16x8 a = *(const bf16x8*)&Om[(wid * 16 + lr) * 136 + ks * 32 + lk];
#pragma unroll
    for (int nt = 0; nt < 8; ++nt) {
      bf16x8 bfr = *(const bf16x8*)&Pw[(nt * 16 + lr) * 136 + ks * 32 + lk];
      acc[nt] = mfma_bf16(a, bfr, acc[nt]);
    }
  }
  float* obase = attn_out + (size_t)wn * 6272;   // 49*128 fp32 per window
#pragma unroll
  for (int nt = 0; nt < 8; ++nt) {
    float bs = pb[nt * 16 + lr];
#pragma unroll
    for (int r4 = 0; r4 < 4; ++r4) {
      int rown = myrow + r4;
      if (rown < WA)
        obase[rown * 128 + nt * 16 + lr] = acc[nt][r4] + bs;
    }
  }
}

// ---------------------------------------------------------------------------
// launch
// ---------------------------------------------------------------------------
extern "C" void kernel_launch(void* const* d_in, const int* in_sizes, int n_in,
                              void* d_out, int out_size, void* d_ws, size_t ws_size,
                              hipStream_t stream) {
  const float* x0 = (const float*)d_in[0];
  const float* x1 = (const float*)d_in[1];
  const float* qkv_w = (const float*)d_in[2];
  const float* qkv_b = (const float*)d_in[3];
  const float* proj_w = (const float*)d_in[4];
  const float* proj_b = (const float*)d_in[5];
  const float* rpb0_w1 = (const float*)d_in[6];
  const float* rpb0_b1 = (const float*)d_in[7];
  const float* rpb0_w2 = (const float*)d_in[8];
  const float* rpb0_b2 = (const float*)d_in[9];
  const float* rpb1_w1 = (const float*)d_in[10];
  const float* rpb1_b1 = (const float*)d_in[11];
  const float* rpb1_w2 = (const float*)d_in[12];
  const float* rpb1_b2 = (const float*)d_in[13];
  const float* coords0 = (const float*)d_in[14];
  const float* coords1 = (const float*)d_in[15];
  const int* idx0 = (const int*)d_in[16];
  const int* idx1 = (const int*)d_in[17];

  // workspace: 56.75 MB (< 58.86 MB known-good)
  char* ws = (char*)d_ws;
  bf16_t* k0 = (bf16_t*)(ws + 0);               // 25,690,112
  bf16_t* v0 = (bf16_t*)(ws + 25690112);        // 25,690,112
  bf16_t* k1 = (bf16_t*)(ws + 51380224);        //    524,288
  bf16_t* v1 = (bf16_t*)(ws + 51904512);        //    524,288
  bf16_t* rpb2 = (bf16_t*)(ws + 52428800);      //  4,194,304
  bf16_t* wq = (bf16_t*)(ws + 56623104);        //     98,304
  bf16_t* pwb = (bf16_t*)(ws + 56721408);       //     32,768 -> end 56,754,176

  k_prep<<<256, 256, 0, stream>>>(qkv_w, proj_w, wq, pwb);
  k_rpb<<<1568, 256, 0, stream>>>(coords0, coords1, rpb0_w1, rpb0_b1, rpb0_w2,
                                  rpb0_b2, rpb1_w1, rpb1_b1, rpb1_w2, rpb1_b2,
                                  rpb2);
  k_qkv<<<1600, 256, 0, stream>>>(x0, x1, wq, qkv_b,
                                  (bf16_t*)d_out, k0, v0, k1, v1);
  k_attn<<<2048, 256, 0, stream>>>((const bf16_t*)d_out, k0, v0, k1, v1,
                                   idx0, idx1, rpb2, pwb, proj_b,
                                   (float*)d_out);
}